// Round 1
// 857.269 us; speedup vs baseline: 1.1086x; 1.1086x over previous
//
#include <hip/hip_runtime.h>
#include <hip/hip_bf16.h>

#define N_SRC 10000
#define N_DST 40000
#define NE    1280000
#define IN_DIM 128
#define O_DIM  300
#define D      64
#define FEAT   64
#define NB     157   // ceil(N_DST/256)

typedef __bf16 bf16x8 __attribute__((ext_vector_type(8)));
typedef __bf16 bf16x4 __attribute__((ext_vector_type(4)));
typedef float  f32x4  __attribute__((ext_vector_type(4)));

// ---------------- K1: z_src = h @ W_fc  [10000x128]@[128x64] ----------------
// 4-row register blocking: one LDS read of w feeds 4 FMAs.
__global__ __launch_bounds__(256) void k_zsrc(const float* __restrict__ h,
                                              const float* __restrict__ Wfc,
                                              float* __restrict__ z,
                                              __bf16* __restrict__ zh){
    __shared__ float w[IN_DIM * D]; // 32 KB
    for (int i = threadIdx.x; i < IN_DIM * D; i += blockDim.x) w[i] = Wfc[i];
    __syncthreads();
    int lane = threadIdx.x & 63;
    int wid  = blockIdx.x * 4 + (threadIdx.x >> 6);
    int nw   = gridDim.x * 4;
    for (int r0 = wid * 4; r0 < N_SRC; r0 += nw * 4){   // N_SRC % 4 == 0
        const f32x4* p0 = (const f32x4*)(h + (size_t)(r0 + 0) * IN_DIM);
        const f32x4* p1 = (const f32x4*)(h + (size_t)(r0 + 1) * IN_DIM);
        const f32x4* p2 = (const f32x4*)(h + (size_t)(r0 + 2) * IN_DIM);
        const f32x4* p3 = (const f32x4*)(h + (size_t)(r0 + 3) * IN_DIM);
        float a0 = 0.f, a1 = 0.f, a2 = 0.f, a3 = 0.f;
        #pragma unroll 4
        for (int k4 = 0; k4 < IN_DIM / 4; ++k4){
            f32x4 v0 = p0[k4], v1 = p1[k4], v2 = p2[k4], v3 = p3[k4];
            #pragma unroll
            for (int i = 0; i < 4; ++i){
                float wv = w[(k4 * 4 + i) * D + lane];
                a0 += v0[i] * wv; a1 += v1[i] * wv;
                a2 += v2[i] * wv; a3 += v3[i] * wv;
            }
        }
        z[(size_t)(r0 + 0) * D + lane] = a0; zh[(size_t)(r0 + 0) * D + lane] = (__bf16)a0;
        z[(size_t)(r0 + 1) * D + lane] = a1; zh[(size_t)(r0 + 1) * D + lane] = (__bf16)a1;
        z[(size_t)(r0 + 2) * D + lane] = a2; zh[(size_t)(r0 + 2) * D + lane] = (__bf16)a2;
        z[(size_t)(r0 + 3) * D + lane] = a3; zh[(size_t)(r0 + 3) * D + lane] = (__bf16)a3;
    }
}

// ---------------- K2: z_dst = o @ W_fc1  [40000x300]@[300x64] ---------------
// 4-row register blocking cuts ds_read count 4x (was LDS-pipe-bound ~40us).
__global__ __launch_bounds__(256) void k_zdst(const float* __restrict__ o,
                                              const float* __restrict__ Wfc1,
                                              float* __restrict__ z){
    extern __shared__ float w[]; // 300*64*4 = 76.8 KB
    for (int i = threadIdx.x; i < O_DIM * D; i += blockDim.x) w[i] = Wfc1[i];
    __syncthreads();
    int lane = threadIdx.x & 63;
    int wid  = blockIdx.x * 4 + (threadIdx.x >> 6);
    int nw   = gridDim.x * 4;
    for (int r0 = wid * 4; r0 < N_DST; r0 += nw * 4){   // N_DST % 4 == 0
        const f32x4* p0 = (const f32x4*)(o + (size_t)(r0 + 0) * O_DIM);
        const f32x4* p1 = (const f32x4*)(o + (size_t)(r0 + 1) * O_DIM);
        const f32x4* p2 = (const f32x4*)(o + (size_t)(r0 + 2) * O_DIM);
        const f32x4* p3 = (const f32x4*)(o + (size_t)(r0 + 3) * O_DIM);
        float a0 = 0.f, a1 = 0.f, a2 = 0.f, a3 = 0.f;
        #pragma unroll 5
        for (int k4 = 0; k4 < O_DIM / 4; ++k4){
            f32x4 v0 = p0[k4], v1 = p1[k4], v2 = p2[k4], v3 = p3[k4];
            #pragma unroll
            for (int i = 0; i < 4; ++i){
                float wv = w[(k4 * 4 + i) * D + lane];
                a0 += v0[i] * wv; a1 += v1[i] * wv;
                a2 += v2[i] * wv; a3 += v3[i] * wv;
            }
        }
        z[(size_t)(r0 + 0) * D + lane] = a0;
        z[(size_t)(r0 + 1) * D + lane] = a1;
        z[(size_t)(r0 + 2) * D + lane] = a2;
        z[(size_t)(r0 + 3) * D + lane] = a3;
    }
}

// ---------------- CSR build: rank-returning histogram -> 3-phase scan -------
// rank[e] = old count => scatter position is csr[d] + rank[e], NO second
// atomic pass and no separate bucket kernel (scatter fused into k_edge).
__global__ __launch_bounds__(256) void k_rank(const int* __restrict__ edst,
                                              int* __restrict__ cnt,
                                              int* __restrict__ rank){
    int i = blockIdx.x * blockDim.x + threadIdx.x;
    if (i < NE) rank[i] = atomicAdd(&cnt[edst[i]], 1);
}

__device__ __forceinline__ int block_incl_scan(int c, int* wsum){
    int lane = threadIdx.x & 63, w = threadIdx.x >> 6;
    int v = c;
    #pragma unroll
    for (int off = 1; off < 64; off <<= 1){
        int u = __shfl_up(v, off);
        if (lane >= off) v += u;
    }
    if (lane == 63) wsum[w] = v;
    __syncthreads();
    int add = 0;
    for (int ww = 0; ww < w; ++ww) add += wsum[ww];
    return v + add;
}

// phase 1: per-block totals
__global__ __launch_bounds__(256) void k_scan1(const int* __restrict__ cnt,
                                               int* __restrict__ bsum){
    __shared__ int wsum[4];
    int i = blockIdx.x * 256 + threadIdx.x;
    int c = (i < N_DST) ? cnt[i] : 0;
    int lane = threadIdx.x & 63, w = threadIdx.x >> 6;
    int v = c;
    #pragma unroll
    for (int off = 1; off < 64; off <<= 1) v += __shfl_xor(v, off);
    if (lane == 0) wsum[w] = v;
    __syncthreads();
    if (threadIdx.x == 0)
        bsum[blockIdx.x] = wsum[0] + wsum[1] + wsum[2] + wsum[3];
}

// phase 2: exclusive scan of the 157 block totals (in place, single block)
__global__ __launch_bounds__(256) void k_scan2(int* __restrict__ bsum){
    __shared__ int wsum[4];
    int i = threadIdx.x;
    int c = (i < NB) ? bsum[i] : 0;
    int v = block_incl_scan(c, wsum);
    if (i < NB) bsum[i] = v - c;   // exclusive
}

// phase 3: full prefix -> csr
__global__ __launch_bounds__(256) void k_scan3(const int* __restrict__ cnt,
                                               const int* __restrict__ bsum,
                                               int* __restrict__ csr){
    __shared__ int wsum[4];
    int i = blockIdx.x * 256 + threadIdx.x;
    int c = (i < N_DST) ? cnt[i] : 0;
    int v = block_incl_scan(c, wsum);
    int val = bsum[blockIdx.x] + v - c;  // exclusive prefix
    if (i < N_DST) csr[i] = val;
    if (blockIdx.x == 0 && threadIdx.x == 0) csr[N_DST] = NE;
}

// ---------------- K3: per-edge attention score, ORIGINAL edge order ---------
// One wave per 16 consecutive edges -> tfidf reads are a sequential 4KB block
// per tile (full-BW stream instead of random 256B gathers). Score + src id
// are scattered directly to the CSR slot csr[dst]+rank (replaces k_bucket).
// MFMA 16x16x32_bf16, C = W_feat^T x tfidf^T.
// C/D layout: col(edge)=lane&15, row(dim)=mt*16 + (lane>>4)*4 + reg.
__global__ __launch_bounds__(256) void k_edge(
        const float* __restrict__ tfidf,
        const int*   __restrict__ esrc, const int* __restrict__ edst,
        const int*   __restrict__ rank, const int* __restrict__ csr,
        const __bf16* __restrict__ zsrch, const float* __restrict__ zdst,
        const float* __restrict__ Wfeat, const float* __restrict__ bfeat,
        const float* __restrict__ Wattn,
        float* __restrict__ escore_p, int* __restrict__ ssrc_s){
    int lane = threadIdx.x & 63;
    int lo = lane & 15, g = lane >> 4;

    // A-frags: A[m=dim][k] = W_feat[k][dim]; lane holds m=mt*16+lo, k=kh*32+g*8+j
    bf16x8 afr[4][2];
    #pragma unroll
    for (int mt = 0; mt < 4; ++mt){
        int m = mt * 16 + lo;
        #pragma unroll
        for (int kh = 0; kh < 2; ++kh){
            #pragma unroll
            for (int j = 0; j < 8; ++j){
                int k = kh * 32 + g * 8 + j;
                afr[mt][kh][j] = (__bf16)Wfeat[k * D + m];
            }
        }
    }
    f32x4 bf4[4], wa4[4];
    #pragma unroll
    for (int mt = 0; mt < 4; ++mt){
        int db = mt * 16 + g * 4;
        bf4[mt] = *(const f32x4*)(bfeat + db);
        wa4[mt] = *(const f32x4*)(Wattn + db);
    }

    int wid = blockIdx.x * 4 + (threadIdx.x >> 6);
    int nw  = gridDim.x * 4;
    for (int tile = wid; tile < NE / 16; tile += nw){
        int e  = tile * 16 + lo;          // this lane's edge (16 consecutive)
        int ss = esrc[e];
        int sd = edst[e];
        int rk = rank[e];

        // B-frags: B[k][n=edge]=tfidf[e][k]; lane n=lo, k=kh*32+g*8+j
        const float* trow = tfidf + (size_t)e * FEAT;
        bf16x8 bfr[2];
        #pragma unroll
        for (int kh = 0; kh < 2; ++kh){
            f32x4 fa = *(const f32x4*)(trow + kh * 32 + g * 8);
            f32x4 fb = *(const f32x4*)(trow + kh * 32 + g * 8 + 4);
            #pragma unroll
            for (int j = 0; j < 4; ++j){
                bfr[kh][j]     = (__bf16)fa[j];
                bfr[kh][4 + j] = (__bf16)fb[j];
            }
        }

        float pacc = 0.f;
        #pragma unroll
        for (int mt = 0; mt < 4; ++mt){
            f32x4 acc = {0.f, 0.f, 0.f, 0.f};
            acc = __builtin_amdgcn_mfma_f32_16x16x32_bf16(afr[mt][0], bfr[0], acc, 0, 0, 0);
            acc = __builtin_amdgcn_mfma_f32_16x16x32_bf16(afr[mt][1], bfr[1], acc, 0, 0, 0);
            int db = mt * 16 + g * 4;
            bf16x4 zs = *(const bf16x4*)(zsrch + (size_t)ss * D + db);
            f32x4  zd = *(const f32x4*)(zdst + (size_t)sd * D + db);
            #pragma unroll
            for (int r = 0; r < 4; ++r){
                float z2 = acc[r] + (float)zs[r] + zd[r] + bf4[mt][r];
                float z3 = z2 > 0.f ? z2 : 0.01f * z2;   // leaky_relu(0.01)
                pacc += z3 * wa4[mt][r];
            }
        }
        pacc += __shfl_xor(pacc, 16);
        pacc += __shfl_xor(pacc, 32);
        if (lane < 16){
            int pos = csr[sd] + rk;       // unique CSR slot for this edge
            escore_p[pos] = pacc;
            ssrc_s[pos]   = ss;
        }
    }
}

// ---------------- K4: fused segment softmax + weighted gather ---------------
// One wave per dst node. lane = dim in the accumulation phase. (unchanged)
__global__ __launch_bounds__(256) void k_post(const int* __restrict__ csr,
                                              const int* __restrict__ ssrc,
                                              const float* __restrict__ escore_p,
                                              const float* __restrict__ zsrc,
                                              float* __restrict__ out){
    int lane = threadIdx.x & 63;
    int d    = blockIdx.x * 4 + (threadIdx.x >> 6);
    if (d >= N_DST) return;
    int beg = csr[d], end = csr[d + 1];

    // pass A: segment max
    float m = -3.4e38f;
    for (int j = beg + lane; j < end; j += 64)
        m = fmaxf(m, escore_p[j]);
    #pragma unroll
    for (int off = 1; off < 64; off <<= 1)
        m = fmaxf(m, __shfl_xor(m, off));

    // pass B: exp-sum
    float ssum = 0.f;
    for (int j = beg + lane; j < end; j += 64)
        ssum += __expf(escore_p[j] - m);
    #pragma unroll
    for (int off = 1; off < 64; off <<= 1)
        ssum += __shfl_xor(ssum, off);
    float inv = 1.f / fmaxf(ssum, 1e-9f);

    // pass C: out[d][lane] = sum_e alpha_e * zsrc[src_e][lane]
    float acc = 0.f;
    for (int base = beg; base < end; base += 64){
        int n = end - base; if (n > 64) n = 64;
        int   sj = 0;
        float aj = 0.f;
        if (base + lane < end){
            sj = ssrc[base + lane];
            aj = __expf(escore_p[base + lane] - m) * inv;
        }
        for (int t = 0; t < n; ++t){
            int   s = __shfl(sj, t);
            float a = __shfl(aj, t);
            acc += a * zsrc[(size_t)s * D + lane];
        }
    }
    out[(size_t)d * D + lane] = acc;
}

extern "C" void kernel_launch(void* const* d_in, const int* in_sizes, int n_in,
                              void* d_out, int out_size, void* d_ws, size_t ws_size,
                              hipStream_t stream) {
    const float* h     = (const float*)d_in[0];
    const float* o     = (const float*)d_in[1];
    const float* tfidf = (const float*)d_in[2];
    const float* Wfc   = (const float*)d_in[3];
    const float* Wfc1  = (const float*)d_in[4];
    const float* Wfeat = (const float*)d_in[5];
    const float* bfeat = (const float*)d_in[6];
    const float* Wattn = (const float*)d_in[7];
    const int*   esrc  = (const int*)d_in[8];
    const int*   edst  = (const int*)d_in[9];
    float* out = (float*)d_out;

    // workspace layout (4B units), ~30 MB total
    float*  ws      = (float*)d_ws;
    float*  zsrc    = ws;                                  // 640000
    float*  zdst    = ws + 640000;                         // 2560000
    __bf16* zsrch   = (__bf16*)(ws + 3200000);             // 320000 (bf16 x 640000)
    float*  escorep = ws + 3520000;                        // 1280000
    int*    ssrc    = (int*)(ws + 4800000);                // 1280000
    int*    rank    = (int*)(ws + 6080000);                // 1280000
    int*    cnt     = (int*)(ws + 7360000);                // 40000
    int*    csr     = (int*)(ws + 7400000);                // 40001
    int*    bsum    = (int*)(ws + 7440002);                // NB

    hipMemsetAsync(cnt, 0, N_DST * sizeof(int), stream);

    k_zsrc<<<256, 256, 0, stream>>>(h, Wfc, zsrc, zsrch);
    k_zdst<<<512, 256, O_DIM * D * sizeof(float), stream>>>(o, Wfc1, zdst);
    k_rank<<<NE / 256, 256, 0, stream>>>(edst, cnt, rank);
    k_scan1<<<NB, 256, 0, stream>>>(cnt, bsum);
    k_scan2<<<1, 256, 0, stream>>>(bsum);
    k_scan3<<<NB, 256, 0, stream>>>(cnt, bsum, csr);
    k_edge<<<4096, 256, 0, stream>>>(tfidf, esrc, edst, rank, csr, zsrch, zdst,
                                     Wfeat, bfeat, Wattn, escorep, ssrc);
    k_post<<<N_DST / 4, 256, 0, stream>>>(csr, ssrc, escorep, zsrc, out);
}

// Round 2
// 806.625 us; speedup vs baseline: 1.1782x; 1.0628x over previous
//
#include <hip/hip_runtime.h>
#include <hip/hip_bf16.h>

#define N_SRC 10000
#define N_DST 40000
#define NE    1280000
#define IN_DIM 128
#define O_DIM  300
#define D      64
#define FEAT   64
#define NB     157   // ceil(N_DST/256)

typedef __bf16 bf16x8 __attribute__((ext_vector_type(8)));
typedef __bf16 bf16x4 __attribute__((ext_vector_type(4)));
typedef float  f32x4  __attribute__((ext_vector_type(4)));

// ---------------- K1: z_src = h @ W_fc  [10000x128]@[128x64] ----------------
// 4-row register blocking: one LDS read of w feeds 4 FMAs.
__global__ __launch_bounds__(256) void k_zsrc(const float* __restrict__ h,
                                              const float* __restrict__ Wfc,
                                              float* __restrict__ z,
                                              __bf16* __restrict__ zh){
    __shared__ float w[IN_DIM * D]; // 32 KB
    for (int i = threadIdx.x; i < IN_DIM * D; i += blockDim.x) w[i] = Wfc[i];
    __syncthreads();
    int lane = threadIdx.x & 63;
    int wid  = blockIdx.x * 4 + (threadIdx.x >> 6);
    int nw   = gridDim.x * 4;
    for (int r0 = wid * 4; r0 < N_SRC; r0 += nw * 4){   // N_SRC % 4 == 0
        const f32x4* p0 = (const f32x4*)(h + (size_t)(r0 + 0) * IN_DIM);
        const f32x4* p1 = (const f32x4*)(h + (size_t)(r0 + 1) * IN_DIM);
        const f32x4* p2 = (const f32x4*)(h + (size_t)(r0 + 2) * IN_DIM);
        const f32x4* p3 = (const f32x4*)(h + (size_t)(r0 + 3) * IN_DIM);
        float a0 = 0.f, a1 = 0.f, a2 = 0.f, a3 = 0.f;
        #pragma unroll 4
        for (int k4 = 0; k4 < IN_DIM / 4; ++k4){
            f32x4 v0 = p0[k4], v1 = p1[k4], v2 = p2[k4], v3 = p3[k4];
            #pragma unroll
            for (int i = 0; i < 4; ++i){
                float wv = w[(k4 * 4 + i) * D + lane];
                a0 += v0[i] * wv; a1 += v1[i] * wv;
                a2 += v2[i] * wv; a3 += v3[i] * wv;
            }
        }
        z[(size_t)(r0 + 0) * D + lane] = a0; zh[(size_t)(r0 + 0) * D + lane] = (__bf16)a0;
        z[(size_t)(r0 + 1) * D + lane] = a1; zh[(size_t)(r0 + 1) * D + lane] = (__bf16)a1;
        z[(size_t)(r0 + 2) * D + lane] = a2; zh[(size_t)(r0 + 2) * D + lane] = (__bf16)a2;
        z[(size_t)(r0 + 3) * D + lane] = a3; zh[(size_t)(r0 + 3) * D + lane] = (__bf16)a3;
    }
}

// ---------------- K2: z_dst = o @ W_fc1  [40000x300]@[300x64] ---------------
// 4-row register blocking cuts ds_read count 4x.
__global__ __launch_bounds__(256) void k_zdst(const float* __restrict__ o,
                                              const float* __restrict__ Wfc1,
                                              float* __restrict__ z){
    extern __shared__ float w[]; // 300*64*4 = 76.8 KB
    for (int i = threadIdx.x; i < O_DIM * D; i += blockDim.x) w[i] = Wfc1[i];
    __syncthreads();
    int lane = threadIdx.x & 63;
    int wid  = blockIdx.x * 4 + (threadIdx.x >> 6);
    int nw   = gridDim.x * 4;
    for (int r0 = wid * 4; r0 < N_DST; r0 += nw * 4){   // N_DST % 4 == 0
        const f32x4* p0 = (const f32x4*)(o + (size_t)(r0 + 0) * O_DIM);
        const f32x4* p1 = (const f32x4*)(o + (size_t)(r0 + 1) * O_DIM);
        const f32x4* p2 = (const f32x4*)(o + (size_t)(r0 + 2) * O_DIM);
        const f32x4* p3 = (const f32x4*)(o + (size_t)(r0 + 3) * O_DIM);
        float a0 = 0.f, a1 = 0.f, a2 = 0.f, a3 = 0.f;
        #pragma unroll 5
        for (int k4 = 0; k4 < O_DIM / 4; ++k4){
            f32x4 v0 = p0[k4], v1 = p1[k4], v2 = p2[k4], v3 = p3[k4];
            #pragma unroll
            for (int i = 0; i < 4; ++i){
                float wv = w[(k4 * 4 + i) * D + lane];
                a0 += v0[i] * wv; a1 += v1[i] * wv;
                a2 += v2[i] * wv; a3 += v3[i] * wv;
            }
        }
        z[(size_t)(r0 + 0) * D + lane] = a0;
        z[(size_t)(r0 + 1) * D + lane] = a1;
        z[(size_t)(r0 + 2) * D + lane] = a2;
        z[(size_t)(r0 + 3) * D + lane] = a3;
    }
}

// ---------------- CSR build: rank-returning histogram -> 3-phase scan -------
__global__ __launch_bounds__(256) void k_rank(const int* __restrict__ edst,
                                              int* __restrict__ cnt,
                                              int* __restrict__ rank){
    int i = blockIdx.x * blockDim.x + threadIdx.x;
    if (i < NE) rank[i] = atomicAdd(&cnt[edst[i]], 1);
}

__device__ __forceinline__ int block_incl_scan(int c, int* wsum){
    int lane = threadIdx.x & 63, w = threadIdx.x >> 6;
    int v = c;
    #pragma unroll
    for (int off = 1; off < 64; off <<= 1){
        int u = __shfl_up(v, off);
        if (lane >= off) v += u;
    }
    if (lane == 63) wsum[w] = v;
    __syncthreads();
    int add = 0;
    for (int ww = 0; ww < w; ++ww) add += wsum[ww];
    return v + add;
}

// phase 1: per-block totals
__global__ __launch_bounds__(256) void k_scan1(const int* __restrict__ cnt,
                                               int* __restrict__ bsum){
    __shared__ int wsum[4];
    int i = blockIdx.x * 256 + threadIdx.x;
    int c = (i < N_DST) ? cnt[i] : 0;
    int lane = threadIdx.x & 63, w = threadIdx.x >> 6;
    int v = c;
    #pragma unroll
    for (int off = 1; off < 64; off <<= 1) v += __shfl_xor(v, off);
    if (lane == 0) wsum[w] = v;
    __syncthreads();
    if (threadIdx.x == 0)
        bsum[blockIdx.x] = wsum[0] + wsum[1] + wsum[2] + wsum[3];
}

// phase 2: exclusive scan of the 157 block totals (in place, single block)
__global__ __launch_bounds__(256) void k_scan2(int* __restrict__ bsum){
    __shared__ int wsum[4];
    int i = threadIdx.x;
    int c = (i < NB) ? bsum[i] : 0;
    int v = block_incl_scan(c, wsum);
    if (i < NB) bsum[i] = v - c;   // exclusive
}

// phase 3: full prefix -> csr
__global__ __launch_bounds__(256) void k_scan3(const int* __restrict__ cnt,
                                               const int* __restrict__ bsum,
                                               int* __restrict__ csr){
    __shared__ int wsum[4];
    int i = blockIdx.x * 256 + threadIdx.x;
    int c = (i < N_DST) ? cnt[i] : 0;
    int v = block_incl_scan(c, wsum);
    int val = bsum[blockIdx.x] + v - c;  // exclusive prefix
    if (i < N_DST) csr[i] = val;
    if (blockIdx.x == 0 && threadIdx.x == 0) csr[N_DST] = NE;
}

// ---------------- K3: per-edge attention score, ORIGINAL edge order ---------
// Software-pipelined: next tile's indices (+csr slot) prefetch during the
// current tile's compute, so the zs/zd gathers issue with addresses ready at
// iteration top and their ~600cy latency hides under tfidf load + cvt + MFMA.
// tfidf is a pure 327MB one-shot stream -> nontemporal loads (keeps the
// zdst/zsrch tables resident in L2/IF$).
// MFMA 16x16x32_bf16, C = W_feat^T x tfidf^T.
// C/D layout: col(edge)=lane&15, row(dim)=mt*16 + (lane>>4)*4 + reg.
__global__ __launch_bounds__(256) void k_edge(
        const float* __restrict__ tfidf,
        const int*   __restrict__ esrc, const int* __restrict__ edst,
        const int*   __restrict__ rank, const int* __restrict__ csr,
        const __bf16* __restrict__ zsrch, const float* __restrict__ zdst,
        const float* __restrict__ Wfeat, const float* __restrict__ bfeat,
        const float* __restrict__ Wattn,
        float* __restrict__ escore_p, int* __restrict__ ssrc_s){
    int lane = threadIdx.x & 63;
    int lo = lane & 15, g = lane >> 4;

    // A-frags: A[m=dim][k] = W_feat[k][dim]; lane holds m=mt*16+lo, k=kh*32+g*8+j
    bf16x8 afr[4][2];
    #pragma unroll
    for (int mt = 0; mt < 4; ++mt){
        int m = mt * 16 + lo;
        #pragma unroll
        for (int kh = 0; kh < 2; ++kh){
            #pragma unroll
            for (int j = 0; j < 8; ++j){
                int k = kh * 32 + g * 8 + j;
                afr[mt][kh][j] = (__bf16)Wfeat[k * D + m];
            }
        }
    }
    f32x4 bf4[4], wa4[4];
    #pragma unroll
    for (int mt = 0; mt < 4; ++mt){
        int db = mt * 16 + g * 4;
        bf4[mt] = *(const f32x4*)(bfeat + db);
        wa4[mt] = *(const f32x4*)(Wattn + db);
    }

    const int NT = NE / 16;
    int wid = blockIdx.x * 4 + (threadIdx.x >> 6);
    int nw  = gridDim.x * 4;

    // ---- pipeline prologue: prefetch tile0's indices + CSR slot ----
    int tile = wid;
    int nss = 0, nsd = 0, npos = 0;
    if (tile < NT){
        int e = tile * 16 + lo;
        nss = esrc[e]; nsd = edst[e];
        npos = csr[nsd] + rank[e];
    }

    for (; tile < NT; tile += nw){
        int css = nss, csd = nsd, cpos = npos;

        // issue current tile's gathers immediately (addresses prefetched)
        bf16x4 zs[4]; f32x4 zd[4];
        #pragma unroll
        for (int mt = 0; mt < 4; ++mt){
            int db = mt * 16 + g * 4;
            zs[mt] = *(const bf16x4*)(zsrch + (size_t)css * D + db);
            zd[mt] = *(const f32x4*)(zdst  + (size_t)csd * D + db);
        }

        // issue current tile's tfidf stream loads (nontemporal)
        int e0 = tile * 16 + lo;
        const float* trow = tfidf + (size_t)e0 * FEAT;
        f32x4 fa0 = __builtin_nontemporal_load((const f32x4*)(trow + g * 8));
        f32x4 fb0 = __builtin_nontemporal_load((const f32x4*)(trow + g * 8 + 4));
        f32x4 fa1 = __builtin_nontemporal_load((const f32x4*)(trow + 32 + g * 8));
        f32x4 fb1 = __builtin_nontemporal_load((const f32x4*)(trow + 32 + g * 8 + 4));

        // prefetch next tile's indices + CSR slot (hides under compute below)
        int tn = tile + nw;
        if (tn < NT){
            int en = tn * 16 + lo;
            nss = esrc[en]; nsd = edst[en];
            npos = csr[nsd] + rank[en];
        }

        // convert tfidf to bf16 B-frags
        bf16x8 bfr[2];
        #pragma unroll
        for (int j = 0; j < 4; ++j){
            bfr[0][j]     = (__bf16)fa0[j];
            bfr[0][4 + j] = (__bf16)fb0[j];
            bfr[1][j]     = (__bf16)fa1[j];
            bfr[1][4 + j] = (__bf16)fb1[j];
        }

        float pacc = 0.f;
        #pragma unroll
        for (int mt = 0; mt < 4; ++mt){
            f32x4 acc = {0.f, 0.f, 0.f, 0.f};
            acc = __builtin_amdgcn_mfma_f32_16x16x32_bf16(afr[mt][0], bfr[0], acc, 0, 0, 0);
            acc = __builtin_amdgcn_mfma_f32_16x16x32_bf16(afr[mt][1], bfr[1], acc, 0, 0, 0);
            #pragma unroll
            for (int r = 0; r < 4; ++r){
                float z2 = acc[r] + (float)zs[mt][r] + zd[mt][r] + bf4[mt][r];
                float z3 = z2 > 0.f ? z2 : 0.01f * z2;   // leaky_relu(0.01)
                pacc += z3 * wa4[mt][r];
            }
        }
        pacc += __shfl_xor(pacc, 16);
        pacc += __shfl_xor(pacc, 32);
        if (lane < 16){
            escore_p[cpos] = pacc;
            ssrc_s[cpos]   = css;
        }
    }
}

// ---------------- K4: fused segment softmax + weighted gather ---------------
// One wave per dst node. Pass C hand-unrolled x4 so four independent zsrc
// row-gathers are in flight per step (was 1 -> latency-serialized).
__global__ __launch_bounds__(256) void k_post(const int* __restrict__ csr,
                                              const int* __restrict__ ssrc,
                                              const float* __restrict__ escore_p,
                                              const float* __restrict__ zsrc,
                                              float* __restrict__ out){
    int lane = threadIdx.x & 63;
    int d    = blockIdx.x * 4 + (threadIdx.x >> 6);
    if (d >= N_DST) return;
    int beg = csr[d], end = csr[d + 1];

    // pass A: segment max
    float m = -3.4e38f;
    for (int j = beg + lane; j < end; j += 64)
        m = fmaxf(m, escore_p[j]);
    #pragma unroll
    for (int off = 1; off < 64; off <<= 1)
        m = fmaxf(m, __shfl_xor(m, off));

    // pass B: exp-sum
    float ssum = 0.f;
    for (int j = beg + lane; j < end; j += 64)
        ssum += __expf(escore_p[j] - m);
    #pragma unroll
    for (int off = 1; off < 64; off <<= 1)
        ssum += __shfl_xor(ssum, off);
    float inv = 1.f / fmaxf(ssum, 1e-9f);

    // pass C: out[d][lane] = sum_e alpha_e * zsrc[src_e][lane]
    float acc = 0.f;
    for (int base = beg; base < end; base += 64){
        int n = end - base; if (n > 64) n = 64;
        int   sj = 0;
        float aj = 0.f;
        if (base + lane < end){
            sj = ssrc[base + lane];
            aj = __expf(escore_p[base + lane] - m) * inv;
        }
        int t = 0;
        for (; t + 4 <= n; t += 4){
            int   s0 = __shfl(sj, t + 0), s1 = __shfl(sj, t + 1);
            int   s2 = __shfl(sj, t + 2), s3 = __shfl(sj, t + 3);
            float a0 = __shfl(aj, t + 0), a1 = __shfl(aj, t + 1);
            float a2 = __shfl(aj, t + 2), a3 = __shfl(aj, t + 3);
            float v0 = zsrc[(size_t)s0 * D + lane];
            float v1 = zsrc[(size_t)s1 * D + lane];
            float v2 = zsrc[(size_t)s2 * D + lane];
            float v3 = zsrc[(size_t)s3 * D + lane];
            acc += a0 * v0; acc += a1 * v1; acc += a2 * v2; acc += a3 * v3;
        }
        for (; t < n; ++t){
            int   s = __shfl(sj, t);
            float a = __shfl(aj, t);
            acc += a * zsrc[(size_t)s * D + lane];
        }
    }
    out[(size_t)d * D + lane] = acc;
}

extern "C" void kernel_launch(void* const* d_in, const int* in_sizes, int n_in,
                              void* d_out, int out_size, void* d_ws, size_t ws_size,
                              hipStream_t stream) {
    const float* h     = (const float*)d_in[0];
    const float* o     = (const float*)d_in[1];
    const float* tfidf = (const float*)d_in[2];
    const float* Wfc   = (const float*)d_in[3];
    const float* Wfc1  = (const float*)d_in[4];
    const float* Wfeat = (const float*)d_in[5];
    const float* bfeat = (const float*)d_in[6];
    const float* Wattn = (const float*)d_in[7];
    const int*   esrc  = (const int*)d_in[8];
    const int*   edst  = (const int*)d_in[9];
    float* out = (float*)d_out;

    // workspace layout (4B units), ~30 MB total
    float*  ws      = (float*)d_ws;
    float*  zsrc    = ws;                                  // 640000
    float*  zdst    = ws + 640000;                         // 2560000
    __bf16* zsrch   = (__bf16*)(ws + 3200000);             // 320000 (bf16 x 640000)
    float*  escorep = ws + 3520000;                        // 1280000
    int*    ssrc    = (int*)(ws + 4800000);                // 1280000
    int*    rank    = (int*)(ws + 6080000);                // 1280000
    int*    cnt     = (int*)(ws + 7360000);                // 40000
    int*    csr     = (int*)(ws + 7400000);                // 40001
    int*    bsum    = (int*)(ws + 7440002);                // NB

    hipMemsetAsync(cnt, 0, N_DST * sizeof(int), stream);

    k_zsrc<<<256, 256, 0, stream>>>(h, Wfc, zsrc, zsrch);
    k_zdst<<<512, 256, O_DIM * D * sizeof(float), stream>>>(o, Wfc1, zdst);
    k_rank<<<NE / 256, 256, 0, stream>>>(edst, cnt, rank);
    k_scan1<<<NB, 256, 0, stream>>>(cnt, bsum);
    k_scan2<<<1, 256, 0, stream>>>(bsum);
    k_scan3<<<NB, 256, 0, stream>>>(cnt, bsum, csr);
    k_edge<<<2048, 256, 0, stream>>>(tfidf, esrc, edst, rank, csr, zsrch, zdst,
                                     Wfeat, bfeat, Wattn, escorep, ssrc);
    k_post<<<N_DST / 4, 256, 0, stream>>>(csr, ssrc, escorep, zsrc, out);
}